// Round 2
// baseline (840.791 us; speedup 1.0000x reference)
//
#include <hip/hip_runtime.h>
#include <hip/hip_bf16.h>
#include <math.h>

// ---------------------------------------------------------------------------
// TransformerBlock on MI355X (gfx950).
// Pipeline: [weight transpose-cvt] -> LN1 -> QKV GEMM -> V-transpose ->
//           flash attn (no-barrier) -> O-proj GEMM(+bias+resid) -> LN2 ->
//           FFN1 GEMM(+bias,gelu) -> FFN2 GEMM(+bias+resid) -> d_out (fp32)
// ---------------------------------------------------------------------------

typedef __attribute__((ext_vector_type(8))) short bf16x8;
typedef __attribute__((ext_vector_type(4))) float f32x4;

#define AS1 __attribute__((address_space(1)))
#define AS3 __attribute__((address_space(3)))

__device__ __forceinline__ void gl_lds16(const void* g, void* l) {
  __builtin_amdgcn_global_load_lds((const AS1 void*)g, (AS3 void*)l, 16, 0, 0);
}

__device__ __forceinline__ float gelu_f(float x) {
  const float c = 0.7978845608028654f;  // sqrt(2/pi)
  return 0.5f * x * (1.0f + tanhf(c * (x + 0.044715f * x * x * x)));
}

// ---------------------------------------------------------------------------
// Weight transpose + fp32->bf16 convert:  W [K,N] fp32  ->  WT [N,K] bf16
// ---------------------------------------------------------------------------
__global__ void __launch_bounds__(256) tcvt_kernel(
    const float* __restrict__ W, __hip_bfloat16* __restrict__ WT, int K, int N) {
  __shared__ float t[32][33];
  const int n0 = blockIdx.x * 32, k0 = blockIdx.y * 32;
  const int tx = threadIdx.x, ty0 = threadIdx.y;  // 32 x 8
#pragma unroll
  for (int i = 0; i < 4; i++) {
    int ty = ty0 + i * 8;
    t[ty][tx] = W[(size_t)(k0 + ty) * N + n0 + tx];
  }
  __syncthreads();
#pragma unroll
  for (int i = 0; i < 4; i++) {
    int ty = ty0 + i * 8;
    WT[(size_t)(n0 + ty) * K + k0 + tx] = __float2bfloat16(t[tx][ty]);
  }
}

// ---------------------------------------------------------------------------
// V transpose: qkv[b*2048+s][3072] (V at col 2048+h*64+hd) -> vt[(bh*64+hd)][s]
// ---------------------------------------------------------------------------
__global__ void __launch_bounds__(256) vtr_kernel(
    const __hip_bfloat16* __restrict__ qkv, __hip_bfloat16* __restrict__ vt) {
  __shared__ __hip_bfloat16 t[32][33];
  const int s0 = blockIdx.x * 32;
  const int hd0 = blockIdx.y * 32;
  const int bh = blockIdx.z;
  const int b = bh >> 4, h = bh & 15;
  const int tx = threadIdx.x, ty0 = threadIdx.y;  // 32 x 8
  const __hip_bfloat16* src =
      qkv + (size_t)(b * 2048 + s0) * 3072 + 2048 + h * 64 + hd0;
#pragma unroll
  for (int i = 0; i < 4; i++) {
    int ty = ty0 + i * 8;
    t[ty][tx] = src[(size_t)ty * 3072 + tx];  // t[s_local][hd_local]
  }
  __syncthreads();
  __hip_bfloat16* dst = vt + ((size_t)bh * 64 + hd0) * 2048 + s0;
#pragma unroll
  for (int i = 0; i < 4; i++) {
    int ty = ty0 + i * 8;
    dst[(size_t)ty * 2048 + tx] = t[tx][ty];
  }
}

// ---------------------------------------------------------------------------
// LayerNorm over D=1024, one block (256 thr) per row, fp32 in -> bf16 out
// ---------------------------------------------------------------------------
__global__ void __launch_bounds__(256) ln_kernel(
    const float* __restrict__ x, const float* __restrict__ gma,
    const float* __restrict__ bta, __hip_bfloat16* __restrict__ out) {
  const int row = blockIdx.x;
  const int tid = threadIdx.x;
  const float4 v = ((const float4*)(x + (size_t)row * 1024))[tid];
  float s = v.x + v.y + v.z + v.w;
  float s2 = v.x * v.x + v.y * v.y + v.z * v.z + v.w * v.w;
#pragma unroll
  for (int m = 32; m; m >>= 1) {
    s += __shfl_xor(s, m);
    s2 += __shfl_xor(s2, m);
  }
  __shared__ float red[8];
  const int w = tid >> 6, lane = tid & 63;
  if (lane == 0) { red[w] = s; red[4 + w] = s2; }
  __syncthreads();
  s = red[0] + red[1] + red[2] + red[3];
  s2 = red[4] + red[5] + red[6] + red[7];
  const float mu = s * (1.0f / 1024.0f);
  const float var = s2 * (1.0f / 1024.0f) - mu * mu;
  const float rs = rsqrtf(var + 1e-5f);
  const float4 gv = ((const float4*)gma)[tid];
  const float4 bv = ((const float4*)bta)[tid];
  __hip_bfloat16* orow = out + (size_t)row * 1024 + tid * 4;
  orow[0] = __float2bfloat16((v.x - mu) * rs * gv.x + bv.x);
  orow[1] = __float2bfloat16((v.y - mu) * rs * gv.y + bv.y);
  orow[2] = __float2bfloat16((v.z - mu) * rs * gv.z + bv.z);
  orow[3] = __float2bfloat16((v.w - mu) * rs * gv.w + bv.w);
}

// ---------------------------------------------------------------------------
// GEMM: C = A[M,K] * B^T[N,K]  (bf16 in, fp32 acc), 128x128 tile, BK=64.
// EPI 0: C bf16 | EPI 1: C fp32 = .+bias+resid | EPI 2: C bf16 = gelu(.+bias)
// XCD-aware block swizzle (grids are all %8==0).
// ---------------------------------------------------------------------------
#define BM 128
#define BN 128
#define BKG 64

template <int EPI>
__global__ void __launch_bounds__(256) gemm_bt(
    const __hip_bfloat16* __restrict__ A, const __hip_bfloat16* __restrict__ BT,
    void* __restrict__ outp, const float* __restrict__ bias,
    const float* __restrict__ resid, int M, int N, int K) {
  __shared__ __hip_bfloat16 sA[BM * BKG];
  __shared__ __hip_bfloat16 sB[BN * BKG];
  const int tid = threadIdx.x;
  const int lane = tid & 63, w = tid >> 6;
  // XCD swizzle: contiguous chunk of blocks per XCD
  const int nwg = gridDim.x * gridDim.y;
  const int orig = blockIdx.y * gridDim.x + blockIdx.x;
  const int cpx = nwg >> 3;
  const int swz = (orig & 7) * cpx + (orig >> 3);
  const int bm = swz % gridDim.x, bn = swz / gridDim.x;
  const int wr = w >> 1, wc = w & 1;
  const int cr = lane & 15, g = lane >> 4;

  f32x4 acc[4][4];
#pragma unroll
  for (int i = 0; i < 4; i++)
#pragma unroll
    for (int j = 0; j < 4; j++) acc[i][j] = (f32x4){0.f, 0.f, 0.f, 0.f};

  const int chunk_row = lane >> 3;        // 0..7 rows within a 1KB chunk
  const int chunk_col = (lane & 7) * 8;   // bf16 elems within a row

  for (int k0 = 0; k0 < K; k0 += BKG) {
#pragma unroll
    for (int i = 0; i < 4; i++) {
      const int chunk = w * 4 + i;        // 0..15
      const int row = chunk * 8 + chunk_row;
      gl_lds16(A + (size_t)(bm * BM + row) * K + k0 + chunk_col, sA + chunk * 512);
      gl_lds16(BT + (size_t)(bn * BN + row) * K + k0 + chunk_col, sB + chunk * 512);
    }
    __syncthreads();
#pragma unroll
    for (int ks = 0; ks < 2; ks++) {
      bf16x8 a[4], b[4];
#pragma unroll
      for (int m = 0; m < 4; m++)
        a[m] = *(const bf16x8*)(sA + (wr * 64 + m * 16 + cr) * BKG + ks * 32 + g * 8);
#pragma unroll
      for (int n = 0; n < 4; n++)
        b[n] = *(const bf16x8*)(sB + (wc * 64 + n * 16 + cr) * BKG + ks * 32 + g * 8);
#pragma unroll
      for (int m = 0; m < 4; m++)
#pragma unroll
        for (int n = 0; n < 4; n++)
          acc[m][n] = __builtin_amdgcn_mfma_f32_16x16x32_bf16(a[m], b[n], acc[m][n], 0, 0, 0);
    }
    __syncthreads();
  }

  // Epilogue. C/D layout: col = lane&15, row = (lane>>4)*4 + reg.
#pragma unroll
  for (int m = 0; m < 4; m++) {
#pragma unroll
    for (int rr = 0; rr < 4; rr++) {
      const int row = bm * BM + wr * 64 + m * 16 + g * 4 + rr;
#pragma unroll
      for (int n = 0; n < 4; n++) {
        const int col = bn * BN + wc * 64 + n * 16 + cr;
        float v = acc[m][n][rr];
        if (EPI == 0) {
          ((__hip_bfloat16*)outp)[(size_t)row * N + col] = __float2bfloat16(v);
        } else if (EPI == 1) {
          v += bias[col] + resid[(size_t)row * N + col];
          ((float*)outp)[(size_t)row * N + col] = v;
        } else {
          v = gelu_f(v + bias[col]);
          ((__hip_bfloat16*)outp)[(size_t)row * N + col] = __float2bfloat16(v);
        }
      }
    }
  }
}

// ---------------------------------------------------------------------------
// Flash attention, causal, barrier-free. qkv [8192,3072] bf16 (Q|K|V),
// vt [b,h][hd=64][s=2048] bf16 (V transposed). Block = 256 thr (4 waves),
// one (qtile=64 rows, b, h) per block; each wave owns 16 q-rows, fully
// independent (LDS only for per-wave P transpose bounce). KVBLK=64.
// ---------------------------------------------------------------------------
__global__ void __launch_bounds__(256) attn_kernel(
    const __hip_bfloat16* __restrict__ qkv, const __hip_bfloat16* __restrict__ vt,
    __hip_bfloat16* __restrict__ o) {
  __shared__ __hip_bfloat16 pl[4][16][72];   // per-wave P tile, padded
  const int tid = threadIdx.x, lane = tid & 63, w = tid >> 6;
  const int qt = gridDim.x - 1 - blockIdx.x;   // heavy q-tiles first
  const int bh = blockIdx.y;
  const int b = bh >> 4, h = bh & 15;
  const int qr0 = qt * 64 + w * 16;
  const int cr = lane & 15, g = lane >> 4;
  const float NEG = -1e30f;

  // Q fragments (A-frag: row = lane&15, k = g*8 + i (+32 per ksub))
  bf16x8 aq[2];
  {
    const __hip_bfloat16* qp =
        qkv + (size_t)(b * 2048 + qr0 + cr) * 3072 + h * 64 + g * 8;
    aq[0] = *(const bf16x8*)qp;
    aq[1] = *(const bf16x8*)(qp + 32);
  }
  const __hip_bfloat16* vbase = vt + (size_t)bh * 64 * 2048;

  f32x4 oacc[4];
#pragma unroll
  for (int i = 0; i < 4; i++) oacc[i] = (f32x4){0.f, 0.f, 0.f, 0.f};
  float mrow[4] = {NEG, NEG, NEG, NEG};
  float lrow[4] = {0.f, 0.f, 0.f, 0.f};

  for (int kt = 0; kt <= qt; kt++) {
    const int kvb = kt * 64;
    // ---- S = (Q K^T) * 0.125 : K b-frags straight from global ----
    f32x4 s[4];
#pragma unroll
    for (int nf = 0; nf < 4; nf++) {
      const __hip_bfloat16* kp =
          qkv + (size_t)(b * 2048 + kvb + nf * 16 + cr) * 3072 + 1024 + h * 64 + g * 8;
      bf16x8 bk0 = *(const bf16x8*)kp;
      bf16x8 bk1 = *(const bf16x8*)(kp + 32);
      f32x4 z = (f32x4){0.f, 0.f, 0.f, 0.f};
      z = __builtin_amdgcn_mfma_f32_16x16x32_bf16(aq[0], bk0, z, 0, 0, 0);
      z = __builtin_amdgcn_mfma_f32_16x16x32_bf16(aq[1], bk1, z, 0, 0, 0);
      s[nf] = z * 0.125f;
    }
    // ---- causal mask (diagonal tile only) ----
    if (kt == qt) {
#pragma unroll
      for (int nf = 0; nf < 4; nf++)
#pragma unroll
        for (int rr = 0; rr < 4; rr++) {
          const int kvcol = kvb + nf * 16 + cr;
          const int qrow = qr0 + g * 4 + rr;
          if (kvcol > qrow) s[nf][rr] = NEG;
        }
    }
    // ---- online softmax (rows g*4+rr; reduce across the 16-lane group) ----
    float scl[4];
#pragma unroll
    for (int rr = 0; rr < 4; rr++) {
      float v = fmaxf(fmaxf(s[0][rr], s[1][rr]), fmaxf(s[2][rr], s[3][rr]));
      v = fmaxf(v, __shfl_xor(v, 1));
      v = fmaxf(v, __shfl_xor(v, 2));
      v = fmaxf(v, __shfl_xor(v, 4));
      v = fmaxf(v, __shfl_xor(v, 8));
      const float mn = fmaxf(mrow[rr], v);
      scl[rr] = __expf(mrow[rr] - mn);
      mrow[rr] = mn;
    }
    float rsum[4] = {0.f, 0.f, 0.f, 0.f};
#pragma unroll
    for (int nf = 0; nf < 4; nf++)
#pragma unroll
      for (int rr = 0; rr < 4; rr++) {
        const float p = __expf(s[nf][rr] - mrow[rr]);
        s[nf][rr] = p;
        rsum[rr] += p;
      }
#pragma unroll
    for (int rr = 0; rr < 4; rr++) {
      float v = rsum[rr];
      v += __shfl_xor(v, 1);
      v += __shfl_xor(v, 2);
      v += __shfl_xor(v, 4);
      v += __shfl_xor(v, 8);
      lrow[rr] = lrow[rr] * scl[rr] + v;
    }
#pragma unroll
    for (int nf = 0; nf < 4; nf++) {
      f32x4 t = oacc[nf];
      t[0] *= scl[0]; t[1] *= scl[1]; t[2] *= scl[2]; t[3] *= scl[3];
      oacc[nf] = t;
    }
    // ---- P -> LDS (per-wave region, no barrier), read back as A-frags ----
#pragma unroll
    for (int nf = 0; nf < 4; nf++)
#pragma unroll
      for (int rr = 0; rr < 4; rr++)
        pl[w][g * 4 + rr][nf * 16 + cr] = __float2bfloat16(s[nf][rr]);
    bf16x8 pa0 = *(const bf16x8*)&pl[w][cr][g * 8];
    bf16x8 pa1 = *(const bf16x8*)&pl[w][cr][g * 8 + 32];
    // ---- O += P V : V b-frags straight from global vt ----
#pragma unroll
    for (int nf = 0; nf < 4; nf++) {
      const __hip_bfloat16* vp = vbase + (size_t)(nf * 16 + cr) * 2048 + kvb + g * 8;
      bf16x8 bv0 = *(const bf16x8*)vp;
      bf16x8 bv1 = *(const bf16x8*)(vp + 32);
      oacc[nf] = __builtin_amdgcn_mfma_f32_16x16x32_bf16(pa0, bv0, oacc[nf], 0, 0, 0);
      oacc[nf] = __builtin_amdgcn_mfma_f32_16x16x32_bf16(pa1, bv1, oacc[nf], 0, 0, 0);
    }
  }

  // ---- write O ----
#pragma unroll
  for (int nf = 0; nf < 4; nf++)
#pragma unroll
    for (int rr = 0; rr < 4; rr++) {
      const int row = qr0 + g * 4 + rr;
      o[(size_t)(b * 2048 + row) * 1024 + h * 64 + nf * 16 + cr] =
          __float2bfloat16(oacc[nf][rr] / lrow[rr]);
    }
}

// ---------------------------------------------------------------------------
// Launch
// ---------------------------------------------------------------------------
extern "C" void kernel_launch(void* const* d_in, const int* in_sizes, int n_in,
                              void* d_out, int out_size, void* d_ws, size_t ws_size,
                              hipStream_t stream) {
  const float* x   = (const float*)d_in[0];
  const float* Wq  = (const float*)d_in[1];
  const float* Wk  = (const float*)d_in[2];
  const float* Wv  = (const float*)d_in[3];
  const float* Wo  = (const float*)d_in[4];
  const float* bo  = (const float*)d_in[5];
  const float* W1  = (const float*)d_in[6];
  const float* b1  = (const float*)d_in[7];
  const float* W2  = (const float*)d_in[8];
  const float* b2  = (const float*)d_in[9];
  const float* g1  = (const float*)d_in[10];
  const float* be1 = (const float*)d_in[11];
  const float* g2  = (const float*)d_in[12];
  const float* be2 = (const float*)d_in[13];

  char* ws = (char*)d_ws;
  const size_t MB = 1024 * 1024;
  __hip_bfloat16* hA    = (__hip_bfloat16*)(ws + 0);          // 16MB (LN1 out)
  __hip_bfloat16* attnO = (__hip_bfloat16*)(ws + 0);          // 16MB (reuse)
  __hip_bfloat16* qkv   = (__hip_bfloat16*)(ws + 16 * MB);    // 48MB
  float*          x2    = (float*)(ws + 16 * MB);             // 32MB (reuse qkv)
  __hip_bfloat16* h2    = (__hip_bfloat16*)(ws + 48 * MB);    // 16MB (reuse qkv tail)
  __hip_bfloat16* vtg   = (__hip_bfloat16*)(ws + 64 * MB);    // 16MB (dead after attn)
  __hip_bfloat16* act   = (__hip_bfloat16*)(ws + 64 * MB);    // 64MB (FFN1 out, after attn)
  __hip_bfloat16* WqkvT = (__hip_bfloat16*)(ws + 128 * MB);   // 6MB  [3072,1024]
  __hip_bfloat16* WoT   = (__hip_bfloat16*)(ws + 134 * MB);   // 2MB  [1024,1024]
  __hip_bfloat16* W1T   = (__hip_bfloat16*)(ws + 136 * MB);   // 8MB  [4096,1024]
  __hip_bfloat16* W2T   = (__hip_bfloat16*)(ws + 144 * MB);   // 8MB  [1024,4096]

  const dim3 tb(32, 8);
  tcvt_kernel<<<dim3(32, 32), tb, 0, stream>>>(Wq, WqkvT, 1024, 1024);
  tcvt_kernel<<<dim3(32, 32), tb, 0, stream>>>(Wk, WqkvT + 1024 * 1024, 1024, 1024);
  tcvt_kernel<<<dim3(32, 32), tb, 0, stream>>>(Wv, WqkvT + 2 * 1024 * 1024, 1024, 1024);
  tcvt_kernel<<<dim3(32, 32), tb, 0, stream>>>(Wo, WoT, 1024, 1024);
  tcvt_kernel<<<dim3(128, 32), tb, 0, stream>>>(W1, W1T, 1024, 4096);
  tcvt_kernel<<<dim3(32, 128), tb, 0, stream>>>(W2, W2T, 4096, 1024);

  ln_kernel<<<8192, 256, 0, stream>>>(x, g1, be1, hA);
  gemm_bt<0><<<dim3(64, 24), 256, 0, stream>>>(hA, WqkvT, qkv, nullptr, nullptr,
                                               8192, 3072, 1024);
  vtr_kernel<<<dim3(64, 2, 64), tb, 0, stream>>>(qkv, vtg);
  attn_kernel<<<dim3(32, 64), 256, 0, stream>>>(qkv, vtg, attnO);
  gemm_bt<1><<<dim3(64, 8), 256, 0, stream>>>(attnO, WoT, x2, bo, x, 8192, 1024, 1024);
  ln_kernel<<<8192, 256, 0, stream>>>(x2, g2, be2, h2);
  gemm_bt<2><<<dim3(64, 32), 256, 0, stream>>>(h2, W1T, act, b1, nullptr,
                                               8192, 4096, 1024);
  gemm_bt<1><<<dim3(64, 8), 256, 0, stream>>>(act, W2T, (float*)d_out, b2, x2,
                                              8192, 1024, 4096);
  (void)in_sizes; (void)n_in; (void)out_size; (void)ws_size;
}

// Round 3
// 562.587 us; speedup vs baseline: 1.4945x; 1.4945x over previous
//
#include <hip/hip_runtime.h>
#include <hip/hip_bf16.h>
#include <math.h>

// ---------------------------------------------------------------------------
// TransformerBlock on MI355X (gfx950).
// Pipeline: [weight transpose-cvt] -> LN1 -> QKV GEMM -> V-transpose ->
//           flash attn (LDS-staged, double-buffered) -> O-proj GEMM(+b+res) ->
//           LN2 -> FFN1 GEMM(+b,gelu) -> FFN2 GEMM(+b+res) -> d_out (fp32)
// ---------------------------------------------------------------------------

typedef __attribute__((ext_vector_type(8))) short bf16x8;
typedef __attribute__((ext_vector_type(4))) float f32x4;

#define AS1 __attribute__((address_space(1)))
#define AS3 __attribute__((address_space(3)))

__device__ __forceinline__ void gl_lds16(const void* g, void* l) {
  __builtin_amdgcn_global_load_lds((const AS1 void*)g, (AS3 void*)l, 16, 0, 0);
}

__device__ __forceinline__ float gelu_f(float x) {
  const float c = 0.7978845608028654f;  // sqrt(2/pi)
  return 0.5f * x * (1.0f + tanhf(c * (x + 0.044715f * x * x * x)));
}

// ---------------------------------------------------------------------------
// Weight transpose + fp32->bf16 convert:  W [K,N] fp32  ->  WT [N,K] bf16
// ---------------------------------------------------------------------------
__global__ void __launch_bounds__(256) tcvt_kernel(
    const float* __restrict__ W, __hip_bfloat16* __restrict__ WT, int K, int N) {
  __shared__ float t[32][33];
  const int n0 = blockIdx.x * 32, k0 = blockIdx.y * 32;
  const int tx = threadIdx.x, ty0 = threadIdx.y;  // 32 x 8
#pragma unroll
  for (int i = 0; i < 4; i++) {
    int ty = ty0 + i * 8;
    t[ty][tx] = W[(size_t)(k0 + ty) * N + n0 + tx];
  }
  __syncthreads();
#pragma unroll
  for (int i = 0; i < 4; i++) {
    int ty = ty0 + i * 8;
    WT[(size_t)(n0 + ty) * K + k0 + tx] = __float2bfloat16(t[tx][ty]);
  }
}

// ---------------------------------------------------------------------------
// V transpose: qkv[b*2048+s][3072] (V at col 2048+h*64+hd) -> vt[(bh*64+hd)][s]
// ---------------------------------------------------------------------------
__global__ void __launch_bounds__(256) vtr_kernel(
    const __hip_bfloat16* __restrict__ qkv, __hip_bfloat16* __restrict__ vt) {
  __shared__ __hip_bfloat16 t[32][33];
  const int s0 = blockIdx.x * 32;
  const int hd0 = blockIdx.y * 32;
  const int bh = blockIdx.z;
  const int b = bh >> 4, h = bh & 15;
  const int tx = threadIdx.x, ty0 = threadIdx.y;  // 32 x 8
  const __hip_bfloat16* src =
      qkv + (size_t)(b * 2048 + s0) * 3072 + 2048 + h * 64 + hd0;
#pragma unroll
  for (int i = 0; i < 4; i++) {
    int ty = ty0 + i * 8;
    t[ty][tx] = src[(size_t)ty * 3072 + tx];  // t[s_local][hd_local]
  }
  __syncthreads();
  __hip_bfloat16* dst = vt + ((size_t)bh * 64 + hd0) * 2048 + s0;
#pragma unroll
  for (int i = 0; i < 4; i++) {
    int ty = ty0 + i * 8;
    dst[(size_t)ty * 2048 + tx] = t[tx][ty];
  }
}

// ---------------------------------------------------------------------------
// LayerNorm over D=1024, one block (256 thr) per row, fp32 in -> bf16 out
// ---------------------------------------------------------------------------
__global__ void __launch_bounds__(256) ln_kernel(
    const float* __restrict__ x, const float* __restrict__ gma,
    const float* __restrict__ bta, __hip_bfloat16* __restrict__ out) {
  const int row = blockIdx.x;
  const int tid = threadIdx.x;
  const float4 v = ((const float4*)(x + (size_t)row * 1024))[tid];
  float s = v.x + v.y + v.z + v.w;
  float s2 = v.x * v.x + v.y * v.y + v.z * v.z + v.w * v.w;
#pragma unroll
  for (int m = 32; m; m >>= 1) {
    s += __shfl_xor(s, m);
    s2 += __shfl_xor(s2, m);
  }
  __shared__ float red[8];
  const int w = tid >> 6, lane = tid & 63;
  if (lane == 0) { red[w] = s; red[4 + w] = s2; }
  __syncthreads();
  s = red[0] + red[1] + red[2] + red[3];
  s2 = red[4] + red[5] + red[6] + red[7];
  const float mu = s * (1.0f / 1024.0f);
  const float var = s2 * (1.0f / 1024.0f) - mu * mu;
  const float rs = rsqrtf(var + 1e-5f);
  const float4 gv = ((const float4*)gma)[tid];
  const float4 bv = ((const float4*)bta)[tid];
  __hip_bfloat16* orow = out + (size_t)row * 1024 + tid * 4;
  orow[0] = __float2bfloat16((v.x - mu) * rs * gv.x + bv.x);
  orow[1] = __float2bfloat16((v.y - mu) * rs * gv.y + bv.y);
  orow[2] = __float2bfloat16((v.z - mu) * rs * gv.z + bv.z);
  orow[3] = __float2bfloat16((v.w - mu) * rs * gv.w + bv.w);
}

// ---------------------------------------------------------------------------
// GEMM: C = A[M,K] * B^T[N,K]  (bf16 in, fp32 acc), 128x128 tile, BK=64.
// EPI 0: C bf16 | EPI 1: C fp32 = .+bias+resid | EPI 2: C bf16 = gelu(.+bias)
// ---------------------------------------------------------------------------
#define BM 128
#define BN 128
#define BKG 64

template <int EPI>
__global__ void __launch_bounds__(256) gemm_bt(
    const __hip_bfloat16* __restrict__ A, const __hip_bfloat16* __restrict__ BT,
    void* __restrict__ outp, const float* __restrict__ bias,
    const float* __restrict__ resid, int M, int N, int K) {
  __shared__ __hip_bfloat16 sA[BM * BKG];
  __shared__ __hip_bfloat16 sB[BN * BKG];
  const int tid = threadIdx.x;
  const int lane = tid & 63, w = tid >> 6;
  // XCD swizzle: contiguous chunk of blocks per XCD
  const int nwg = gridDim.x * gridDim.y;
  const int orig = blockIdx.y * gridDim.x + blockIdx.x;
  const int cpx = nwg >> 3;
  const int swz = (orig & 7) * cpx + (orig >> 3);
  const int bm = swz % gridDim.x, bn = swz / gridDim.x;
  const int wr = w >> 1, wc = w & 1;
  const int cr = lane & 15, g = lane >> 4;

  f32x4 acc[4][4];
#pragma unroll
  for (int i = 0; i < 4; i++)
#pragma unroll
    for (int j = 0; j < 4; j++) acc[i][j] = (f32x4){0.f, 0.f, 0.f, 0.f};

  const int chunk_row = lane >> 3;        // 0..7 rows within a 1KB chunk
  const int chunk_col = (lane & 7) * 8;   // bf16 elems within a row

  for (int k0 = 0; k0 < K; k0 += BKG) {
#pragma unroll
    for (int i = 0; i < 4; i++) {
      const int chunk = w * 4 + i;        // 0..15
      const int row = chunk * 8 + chunk_row;
      gl_lds16(A + (size_t)(bm * BM + row) * K + k0 + chunk_col, sA + chunk * 512);
      gl_lds16(BT + (size_t)(bn * BN + row) * K + k0 + chunk_col, sB + chunk * 512);
    }
    __syncthreads();
#pragma unroll
    for (int ks = 0; ks < 2; ks++) {
      bf16x8 a[4], b[4];
#pragma unroll
      for (int m = 0; m < 4; m++)
        a[m] = *(const bf16x8*)(sA + (wr * 64 + m * 16 + cr) * BKG + ks * 32 + g * 8);
#pragma unroll
      for (int n = 0; n < 4; n++)
        b[n] = *(const bf16x8*)(sB + (wc * 64 + n * 16 + cr) * BKG + ks * 32 + g * 8);
#pragma unroll
      for (int m = 0; m < 4; m++)
#pragma unroll
        for (int n = 0; n < 4; n++)
          acc[m][n] = __builtin_amdgcn_mfma_f32_16x16x32_bf16(a[m], b[n], acc[m][n], 0, 0, 0);
    }
    __syncthreads();
  }

  // Epilogue. C/D layout: col = lane&15, row = (lane>>4)*4 + reg.
#pragma unroll
  for (int m = 0; m < 4; m++) {
#pragma unroll
    for (int rr = 0; rr < 4; rr++) {
      const int row = bm * BM + wr * 64 + m * 16 + g * 4 + rr;
#pragma unroll
      for (int n = 0; n < 4; n++) {
        const int col = bn * BN + wc * 64 + n * 16 + cr;
        float v = acc[m][n][rr];
        if (EPI == 0) {
          ((__hip_bfloat16*)outp)[(size_t)row * N + col] = __float2bfloat16(v);
        } else if (EPI == 1) {
          v += bias[col] + resid[(size_t)row * N + col];
          ((float*)outp)[(size_t)row * N + col] = v;
        } else {
          v = gelu_f(v + bias[col]);
          ((__hip_bfloat16*)outp)[(size_t)row * N + col] = __float2bfloat16(v);
        }
      }
    }
  }
}

// ---------------------------------------------------------------------------
// Flash attention, causal. qkv [8192,3072] bf16 (Q|K|V), vt [bh][hd=64][s]
// (V transposed). Block = 256 thr (4 waves), QBLK=128 (wave owns 32 q-rows,
// 2 m-frags), KVBLK=64. K and V^T tiles staged to LDS via global_load_lds,
// double-buffered (issue next before compute, 1 barrier/iter). exp2-domain
// online softmax. LDS = 2*8K(K) + 2*8K(V^T) + 4*2K(P) = 40KB -> 4 blocks/CU.
// ---------------------------------------------------------------------------
__global__ void __launch_bounds__(256) attn_kernel(
    const __hip_bfloat16* __restrict__ qkv, const __hip_bfloat16* __restrict__ vt,
    __hip_bfloat16* __restrict__ o) {
  __shared__ __hip_bfloat16 sK[2][64 * 64];   // [kv][hd]
  __shared__ __hip_bfloat16 sV[2][64 * 64];   // [hd][kv]
  __shared__ __hip_bfloat16 pl[4][16][64];    // per-wave P bounce
  const int tid = threadIdx.x, lane = tid & 63, w = tid >> 6;
  // XCD-aware mapping: all 16 q-tiles of a head group land on one XCD.
  const int bid = blockIdx.x;                  // 0..1023
  const int bh = (bid & 7) + 8 * ((bid >> 3) & 7);
  const int qt = 15 - (bid >> 6);              // heavy q-tiles first
  const int b = bh >> 4, h = bh & 15;
  const int cr = lane & 15, g = lane >> 4;
  const int qr0 = qt * 128 + w * 32;           // wave's first q row
  const float NEG = -1e30f;
  const float SC2 = 0.18033688011112042f;      // 0.125 * log2(e)

  // Q fragments (A-frag: row = lane&15, k = g*8 + j (+32 per ksub))
  bf16x8 aq[2][2];
#pragma unroll
  for (int m = 0; m < 2; m++) {
    const __hip_bfloat16* qp =
        qkv + (size_t)(b * 2048 + qr0 + m * 16 + cr) * 3072 + h * 64 + g * 8;
    aq[m][0] = *(const bf16x8*)qp;
    aq[m][1] = *(const bf16x8*)(qp + 32);
  }
  const __hip_bfloat16* kbase = qkv + (size_t)(b * 2048) * 3072 + 1024 + h * 64;
  const __hip_bfloat16* vbase = vt + (size_t)bh * 64 * 2048;

  const int l8 = lane >> 3, c8 = lane & 7;
#define STAGE_TILE(bi, ktile)                                                   \
  {                                                                             \
    _Pragma("unroll") for (int i = 0; i < 2; i++) {                             \
      const int rb = (i * 4 + w) * 8 + l8;                                      \
      gl_lds16(kbase + (size_t)((ktile) * 64 + rb) * 3072 + c8 * 8,             \
               &sK[bi][(i * 4 + w) * 512]);                                     \
      gl_lds16(vbase + (size_t)rb * 2048 + (ktile) * 64 + c8 * 8,               \
               &sV[bi][(i * 4 + w) * 512]);                                     \
    }                                                                           \
  }

  f32x4 oacc[2][4];
#pragma unroll
  for (int m = 0; m < 2; m++)
#pragma unroll
    for (int i = 0; i < 4; i++) oacc[m][i] = (f32x4){0.f, 0.f, 0.f, 0.f};
  float mrow[2][4], lrow[2][4];
#pragma unroll
  for (int m = 0; m < 2; m++)
#pragma unroll
    for (int rr = 0; rr < 4; rr++) { mrow[m][rr] = NEG; lrow[m][rr] = 0.f; }

  const int nkt = (qt + 1) * 2;
  STAGE_TILE(0, 0);
  asm volatile("s_waitcnt vmcnt(0)" ::: "memory");
  __syncthreads();
  int cur = 0;

  for (int kt = 0; kt < nkt; ++kt) {
    if (kt + 1 < nkt) STAGE_TILE(cur ^ 1, kt + 1);

    if (kt * 64 <= qr0 + 31) {  // wave has visible keys in this tile
      // ---- S = (Q K^T) * scale, exp2 domain ----
      f32x4 s[2][4];
#pragma unroll
      for (int nf = 0; nf < 4; nf++) {
        const bf16x8 bk0 = *(const bf16x8*)&sK[cur][(nf * 16 + cr) * 64 + g * 8];
        const bf16x8 bk1 = *(const bf16x8*)&sK[cur][(nf * 16 + cr) * 64 + g * 8 + 32];
#pragma unroll
        for (int m = 0; m < 2; m++) {
          f32x4 z = (f32x4){0.f, 0.f, 0.f, 0.f};
          z = __builtin_amdgcn_mfma_f32_16x16x32_bf16(aq[m][0], bk0, z, 0, 0, 0);
          z = __builtin_amdgcn_mfma_f32_16x16x32_bf16(aq[m][1], bk1, z, 0, 0, 0);
          s[m][nf] = z * SC2;
        }
      }
      // ---- causal mask (diagonal region only) ----
      if (kt * 64 + 63 > qr0) {
#pragma unroll
        for (int m = 0; m < 2; m++)
#pragma unroll
          for (int nf = 0; nf < 4; nf++)
#pragma unroll
            for (int rr = 0; rr < 4; rr++) {
              const int kvcol = kt * 64 + nf * 16 + cr;
              const int qrow = qr0 + m * 16 + g * 4 + rr;
              if (kvcol > qrow) s[m][nf][rr] = NEG;
            }
      }
      // ---- per m-frag: online softmax + P bounce + PV ----
#pragma unroll
      for (int m = 0; m < 2; m++) {
        float scl[4];
#pragma unroll
        for (int rr = 0; rr < 4; rr++) {
          float v = fmaxf(fmaxf(s[m][0][rr], s[m][1][rr]),
                          fmaxf(s[m][2][rr], s[m][3][rr]));
          v = fmaxf(v, __shfl_xor(v, 1));
          v = fmaxf(v, __shfl_xor(v, 2));
          v = fmaxf(v, __shfl_xor(v, 4));
          v = fmaxf(v, __shfl_xor(v, 8));
          const float mn = fmaxf(mrow[m][rr], v);
          scl[rr] = exp2f(mrow[m][rr] - mn);
          mrow[m][rr] = mn;
        }
        float rsum[4] = {0.f, 0.f, 0.f, 0.f};
#pragma unroll
        for (int nf = 0; nf < 4; nf++)
#pragma unroll
          for (int rr = 0; rr < 4; rr++) {
            const float p = exp2f(s[m][nf][rr] - mrow[m][rr]);
            s[m][nf][rr] = p;
            rsum[rr] += p;
          }
#pragma unroll
        for (int rr = 0; rr < 4; rr++) {
          float v = rsum[rr];
          v += __shfl_xor(v, 1);
          v += __shfl_xor(v, 2);
          v += __shfl_xor(v, 4);
          v += __shfl_xor(v, 8);
          lrow[m][rr] = lrow[m][rr] * scl[rr] + v;
        }
#pragma unroll
        for (int nf = 0; nf < 4; nf++) {
          f32x4 t = oacc[m][nf];
          t[0] *= scl[0]; t[1] *= scl[1]; t[2] *= scl[2]; t[3] *= scl[3];
          oacc[m][nf] = t;
        }
#pragma unroll
        for (int nf = 0; nf < 4; nf++)
#pragma unroll
          for (int rr = 0; rr < 4; rr++)
            pl[w][g * 4 + rr][nf * 16 + cr] = __float2bfloat16(s[m][nf][rr]);
        const bf16x8 pa0 = *(const bf16x8*)&pl[w][cr][g * 8];
        const bf16x8 pa1 = *(const bf16x8*)&pl[w][cr][g * 8 + 32];
#pragma unroll
        for (int nf = 0; nf < 4; nf++) {
          const bf16x8 bv0 = *(const bf16x8*)&sV[cur][(nf * 16 + cr) * 64 + g * 8];
          const bf16x8 bv1 = *(const bf16x8*)&sV[cur][(nf * 16 + cr) * 64 + g * 8 + 32];
          oacc[m][nf] = __builtin_amdgcn_mfma_f32_16x16x32_bf16(pa0, bv0, oacc[m][nf], 0, 0, 0);
          oacc[m][nf] = __builtin_amdgcn_mfma_f32_16x16x32_bf16(pa1, bv1, oacc[m][nf], 0, 0, 0);
        }
      }
    }

    if (kt + 1 < nkt) {
      asm volatile("s_waitcnt vmcnt(0)" ::: "memory");
      __syncthreads();
      cur ^= 1;
    }
  }

  // ---- write O ----
#pragma unroll
  for (int m = 0; m < 2; m++)
#pragma unroll
    for (int nf = 0; nf < 4; nf++)
#pragma unroll
      for (int rr = 0; rr < 4; rr++) {
        const int row = qr0 + m * 16 + g * 4 + rr;
        o[(size_t)(b * 2048 + row) * 1024 + h * 64 + nf * 16 + cr] =
            __float2bfloat16(oacc[m][nf][rr] / lrow[m][rr]);
      }
#undef STAGE_TILE
}

// ---------------------------------------------------------------------------
// Launch
// ---------------------------------------------------------------------------
extern "C" void kernel_launch(void* const* d_in, const int* in_sizes, int n_in,
                              void* d_out, int out_size, void* d_ws, size_t ws_size,
                              hipStream_t stream) {
  const float* x   = (const float*)d_in[0];
  const float* Wq  = (const float*)d_in[1];
  const float* Wk  = (const float*)d_in[2];
  const float* Wv  = (const float*)d_in[3];
  const float* Wo  = (const float*)d_in[4];
  const float* bo  = (const float*)d_in[5];
  const float* W1  = (const float*)d_in[6];
  const float* b1  = (const float*)d_in[7];
  const float* W2  = (const float*)d_in[8];
  const float* b2  = (const float*)d_in[9];
  const float* g1  = (const float*)d_in[10];
  const float* be1 = (const float*)d_in[11];
  const float* g2  = (const float*)d_in[12];
  const float* be2 = (const float*)d_in[13];

  char* ws = (char*)d_ws;
  const size_t MB = 1024 * 1024;
  __hip_bfloat16* hA    = (__hip_bfloat16*)(ws + 0);          // 16MB (LN1 out)
  __hip_bfloat16* attnO = (__hip_bfloat16*)(ws + 0);          // 16MB (reuse)
  __hip_bfloat16* qkv   = (__hip_bfloat16*)(ws + 16 * MB);    // 48MB
  float*          x2    = (float*)(ws + 16 * MB);             // 32MB (reuse qkv)
  __hip_bfloat16* h2    = (__hip_bfloat16*)(ws + 48 * MB);    // 16MB (reuse qkv tail)
  __hip_bfloat16* vtg   = (__hip_bfloat16*)(ws + 64 * MB);    // 16MB (dead after attn)
  __hip_bfloat16* act   = (__hip_bfloat16*)(ws + 64 * MB);    // 64MB (FFN1 out, after attn)
  __hip_bfloat16* WqkvT = (__hip_bfloat16*)(ws + 128 * MB);   // 6MB  [3072,1024]
  __hip_bfloat16* WoT   = (__hip_bfloat16*)(ws + 134 * MB);   // 2MB  [1024,1024]
  __hip_bfloat16* W1T   = (__hip_bfloat16*)(ws + 136 * MB);   // 8MB  [4096,1024]
  __hip_bfloat16* W2T   = (__hip_bfloat16*)(ws + 144 * MB);   // 8MB  [1024,4096]

  const dim3 tb(32, 8);
  tcvt_kernel<<<dim3(32, 32), tb, 0, stream>>>(Wq, WqkvT, 1024, 1024);
  tcvt_kernel<<<dim3(32, 32), tb, 0, stream>>>(Wk, WqkvT + 1024 * 1024, 1024, 1024);
  tcvt_kernel<<<dim3(32, 32), tb, 0, stream>>>(Wv, WqkvT + 2 * 1024 * 1024, 1024, 1024);
  tcvt_kernel<<<dim3(32, 32), tb, 0, stream>>>(Wo, WoT, 1024, 1024);
  tcvt_kernel<<<dim3(128, 32), tb, 0, stream>>>(W1, W1T, 1024, 4096);
  tcvt_kernel<<<dim3(32, 128), tb, 0, stream>>>(W2, W2T, 4096, 1024);

  ln_kernel<<<8192, 256, 0, stream>>>(x, g1, be1, hA);
  gemm_bt<0><<<dim3(64, 24), 256, 0, stream>>>(hA, WqkvT, qkv, nullptr, nullptr,
                                               8192, 3072, 1024);
  vtr_kernel<<<dim3(64, 2, 64), tb, 0, stream>>>(qkv, vtg);
  attn_kernel<<<1024, 256, 0, stream>>>(qkv, vtg, attnO);
  gemm_bt<1><<<dim3(64, 8), 256, 0, stream>>>(attnO, WoT, x2, bo, x, 8192, 1024, 1024);
  ln_kernel<<<8192, 256, 0, stream>>>(x2, g2, be2, h2);
  gemm_bt<2><<<dim3(64, 32), 256, 0, stream>>>(h2, W1T, act, b1, nullptr,
                                               8192, 4096, 1024);
  gemm_bt<1><<<dim3(64, 8), 256, 0, stream>>>(act, W2T, (float*)d_out, b2, x2,
                                              8192, 1024, 4096);
  (void)in_sizes; (void)n_in; (void)out_size; (void)ws_size;
}

// Round 4
// 531.926 us; speedup vs baseline: 1.5807x; 1.0576x over previous
//
#include <hip/hip_runtime.h>
#include <hip/hip_bf16.h>
#include <math.h>

// ---------------------------------------------------------------------------
// TransformerBlock on MI355X (gfx950).
// Pipeline: [weight transpose-cvt] -> LN1 -> QKV GEMM -> V-transpose ->
//           flash attn (LDS-staged, double-buffered, XOR-swizzled) ->
//           O-proj GEMM(+b+res) -> LN2 -> FFN1 GEMM(+b,gelu) ->
//           FFN2 GEMM(+b+res) -> d_out (fp32)
// ---------------------------------------------------------------------------

typedef __attribute__((ext_vector_type(8))) short bf16x8;
typedef __attribute__((ext_vector_type(4))) float f32x4;

#define AS1 __attribute__((address_space(1)))
#define AS3 __attribute__((address_space(3)))

__device__ __forceinline__ void gl_lds16(const void* g, void* l) {
  __builtin_amdgcn_global_load_lds((const AS1 void*)g, (AS3 void*)l, 16, 0, 0);
}

__device__ __forceinline__ float gelu_f(float x) {
  const float c = 0.7978845608028654f;  // sqrt(2/pi)
  return 0.5f * x * (1.0f + tanhf(c * (x + 0.044715f * x * x * x)));
}

// ---------------------------------------------------------------------------
// Weight transpose + fp32->bf16 convert:  W [K,N] fp32  ->  WT [N,K] bf16
// ---------------------------------------------------------------------------
__global__ void __launch_bounds__(256) tcvt_kernel(
    const float* __restrict__ W, __hip_bfloat16* __restrict__ WT, int K, int N) {
  __shared__ float t[32][33];
  const int n0 = blockIdx.x * 32, k0 = blockIdx.y * 32;
  const int tx = threadIdx.x, ty0 = threadIdx.y;  // 32 x 8
#pragma unroll
  for (int i = 0; i < 4; i++) {
    int ty = ty0 + i * 8;
    t[ty][tx] = W[(size_t)(k0 + ty) * N + n0 + tx];
  }
  __syncthreads();
#pragma unroll
  for (int i = 0; i < 4; i++) {
    int ty = ty0 + i * 8;
    WT[(size_t)(n0 + ty) * K + k0 + tx] = __float2bfloat16(t[tx][ty]);
  }
}

// ---------------------------------------------------------------------------
// V transpose: qkv[b*2048+s][3072] (V at col 2048+h*64+hd) -> vt[(bh*64+hd)][s]
// ---------------------------------------------------------------------------
__global__ void __launch_bounds__(256) vtr_kernel(
    const __hip_bfloat16* __restrict__ qkv, __hip_bfloat16* __restrict__ vt) {
  __shared__ __hip_bfloat16 t[32][33];
  const int s0 = blockIdx.x * 32;
  const int hd0 = blockIdx.y * 32;
  const int bh = blockIdx.z;
  const int b = bh >> 4, h = bh & 15;
  const int tx = threadIdx.x, ty0 = threadIdx.y;  // 32 x 8
  const __hip_bfloat16* src =
      qkv + (size_t)(b * 2048 + s0) * 3072 + 2048 + h * 64 + hd0;
#pragma unroll
  for (int i = 0; i < 4; i++) {
    int ty = ty0 + i * 8;
    t[ty][tx] = src[(size_t)ty * 3072 + tx];  // t[s_local][hd_local]
  }
  __syncthreads();
  __hip_bfloat16* dst = vt + ((size_t)bh * 64 + hd0) * 2048 + s0;
#pragma unroll
  for (int i = 0; i < 4; i++) {
    int ty = ty0 + i * 8;
    dst[(size_t)ty * 2048 + tx] = t[tx][ty];
  }
}

// ---------------------------------------------------------------------------
// LayerNorm over D=1024, one block (256 thr) per row, fp32 in -> bf16 out
// ---------------------------------------------------------------------------
__global__ void __launch_bounds__(256) ln_kernel(
    const float* __restrict__ x, const float* __restrict__ gma,
    const float* __restrict__ bta, __hip_bfloat16* __restrict__ out) {
  const int row = blockIdx.x;
  const int tid = threadIdx.x;
  const float4 v = ((const float4*)(x + (size_t)row * 1024))[tid];
  float s = v.x + v.y + v.z + v.w;
  float s2 = v.x * v.x + v.y * v.y + v.z * v.z + v.w * v.w;
#pragma unroll
  for (int m = 32; m; m >>= 1) {
    s += __shfl_xor(s, m);
    s2 += __shfl_xor(s2, m);
  }
  __shared__ float red[8];
  const int w = tid >> 6, lane = tid & 63;
  if (lane == 0) { red[w] = s; red[4 + w] = s2; }
  __syncthreads();
  s = red[0] + red[1] + red[2] + red[3];
  s2 = red[4] + red[5] + red[6] + red[7];
  const float mu = s * (1.0f / 1024.0f);
  const float var = s2 * (1.0f / 1024.0f) - mu * mu;
  const float rs = rsqrtf(var + 1e-5f);
  const float4 gv = ((const float4*)gma)[tid];
  const float4 bv = ((const float4*)bta)[tid];
  __hip_bfloat16* orow = out + (size_t)row * 1024 + tid * 4;
  orow[0] = __float2bfloat16((v.x - mu) * rs * gv.x + bv.x);
  orow[1] = __float2bfloat16((v.y - mu) * rs * gv.y + bv.y);
  orow[2] = __float2bfloat16((v.z - mu) * rs * gv.z + bv.z);
  orow[3] = __float2bfloat16((v.w - mu) * rs * gv.w + bv.w);
}

// ---------------------------------------------------------------------------
// GEMM: C = A[M,K] * B^T[N,K]  (bf16 in, fp32 acc), 128x128 tile, BK=64.
// EPI 0: C bf16 | EPI 1: C fp32 = .+bias+resid | EPI 2: C bf16 = gelu(.+bias)
// ---------------------------------------------------------------------------
#define BM 128
#define BN 128
#define BKG 64

template <int EPI>
__global__ void __launch_bounds__(256) gemm_bt(
    const __hip_bfloat16* __restrict__ A, const __hip_bfloat16* __restrict__ BT,
    void* __restrict__ outp, const float* __restrict__ bias,
    const float* __restrict__ resid, int M, int N, int K) {
  __shared__ __hip_bfloat16 sA[BM * BKG];
  __shared__ __hip_bfloat16 sB[BN * BKG];
  const int tid = threadIdx.x;
  const int lane = tid & 63, w = tid >> 6;
  // XCD swizzle: contiguous chunk of blocks per XCD
  const int nwg = gridDim.x * gridDim.y;
  const int orig = blockIdx.y * gridDim.x + blockIdx.x;
  const int cpx = nwg >> 3;
  const int swz = (orig & 7) * cpx + (orig >> 3);
  const int bm = swz % gridDim.x, bn = swz / gridDim.x;
  const int wr = w >> 1, wc = w & 1;
  const int cr = lane & 15, g = lane >> 4;

  f32x4 acc[4][4];
#pragma unroll
  for (int i = 0; i < 4; i++)
#pragma unroll
    for (int j = 0; j < 4; j++) acc[i][j] = (f32x4){0.f, 0.f, 0.f, 0.f};

  const int chunk_row = lane >> 3;        // 0..7 rows within a 1KB chunk
  const int chunk_col = (lane & 7) * 8;   // bf16 elems within a row

  for (int k0 = 0; k0 < K; k0 += BKG) {
#pragma unroll
    for (int i = 0; i < 4; i++) {
      const int chunk = w * 4 + i;        // 0..15
      const int row = chunk * 8 + chunk_row;
      gl_lds16(A + (size_t)(bm * BM + row) * K + k0 + chunk_col, sA + chunk * 512);
      gl_lds16(BT + (size_t)(bn * BN + row) * K + k0 + chunk_col, sB + chunk * 512);
    }
    __syncthreads();
#pragma unroll
    for (int ks = 0; ks < 2; ks++) {
      bf16x8 a[4], b[4];
#pragma unroll
      for (int m = 0; m < 4; m++)
        a[m] = *(const bf16x8*)(sA + (wr * 64 + m * 16 + cr) * BKG + ks * 32 + g * 8);
#pragma unroll
      for (int n = 0; n < 4; n++)
        b[n] = *(const bf16x8*)(sB + (wc * 64 + n * 16 + cr) * BKG + ks * 32 + g * 8);
#pragma unroll
      for (int m = 0; m < 4; m++)
#pragma unroll
        for (int n = 0; n < 4; n++)
          acc[m][n] = __builtin_amdgcn_mfma_f32_16x16x32_bf16(a[m], b[n], acc[m][n], 0, 0, 0);
    }
    __syncthreads();
  }

  // Epilogue. C/D layout: col = lane&15, row = (lane>>4)*4 + reg.
#pragma unroll
  for (int m = 0; m < 4; m++) {
#pragma unroll
    for (int rr = 0; rr < 4; rr++) {
      const int row = bm * BM + wr * 64 + m * 16 + g * 4 + rr;
#pragma unroll
      for (int n = 0; n < 4; n++) {
        const int col = bn * BN + wc * 64 + n * 16 + cr;
        float v = acc[m][n][rr];
        if (EPI == 0) {
          ((__hip_bfloat16*)outp)[(size_t)row * N + col] = __float2bfloat16(v);
        } else if (EPI == 1) {
          v += bias[col] + resid[(size_t)row * N + col];
          ((float*)outp)[(size_t)row * N + col] = v;
        } else {
          v = gelu_f(v + bias[col]);
          ((__hip_bfloat16*)outp)[(size_t)row * N + col] = __float2bfloat16(v);
        }
      }
    }
  }
}

// ---------------------------------------------------------------------------
// Flash attention, causal. qkv [8192,3072] bf16 (Q|K|V), vt [bh][hd=64][s]
// (V transposed). Block = 256 thr (4 waves), QBLK=128 (wave owns 32 q-rows,
// 2 m-frags), KVBLK=64. K/V^T staged to LDS via global_load_lds with
// XOR-swizzled SOURCE slots (rule #21: linear LDS dest + inverse-swz source
// + swz on read). Row stride 128B => unswizzled reads were 16-way conflicts.
// Double-buffered, 1 barrier/iter. exp2-domain online softmax.
// ---------------------------------------------------------------------------
__global__ void __launch_bounds__(256) attn_kernel(
    const __hip_bfloat16* __restrict__ qkv, const __hip_bfloat16* __restrict__ vt,
    __hip_bfloat16* __restrict__ o) {
  __shared__ __hip_bfloat16 sK[2][64 * 64];   // [kv][hd], slot-swizzled
  __shared__ __hip_bfloat16 sV[2][64 * 64];   // [hd][kv], slot-swizzled
  __shared__ __hip_bfloat16 pl[4][16][64];    // per-wave P bounce, swizzled
  const int tid = threadIdx.x, lane = tid & 63, w = tid >> 6;
  // XCD-aware mapping: all 16 q-tiles of a head group land on one XCD.
  const int bid = blockIdx.x;                  // 0..1023
  const int bh = (bid & 7) + 8 * ((bid >> 3) & 7);
  const int qt = 15 - (bid >> 6);              // heavy q-tiles first
  const int b = bh >> 4, h = bh & 15;
  const int cr = lane & 15, g = lane >> 4;
  const int qr0 = qt * 128 + w * 32;           // wave's first q row
  const float NEG = -1e30f;
  const float SC2 = 0.18033688011112042f;      // 0.125 * log2(e)
  const int sw = cr & 7;                       // read-side swizzle key
  const int sg0 = (g ^ sw) * 8;                // swizzled 16B slot (elems)
  const int sg1 = ((g ^ sw) ^ 4) * 8;

  // Q fragments (A-frag: row = lane&15, k = g*8 + j (+32 per ksub))
  bf16x8 aq[2][2];
#pragma unroll
  for (int m = 0; m < 2; m++) {
    const __hip_bfloat16* qp =
        qkv + (size_t)(b * 2048 + qr0 + m * 16 + cr) * 3072 + h * 64 + g * 8;
    aq[m][0] = *(const bf16x8*)qp;
    aq[m][1] = *(const bf16x8*)(qp + 32);
  }
  const __hip_bfloat16* kbase = qkv + (size_t)(b * 2048) * 3072 + 1024 + h * 64;
  const __hip_bfloat16* vbase = vt + (size_t)bh * 64 * 2048;

  const int l8 = lane >> 3, c8 = lane & 7;
  const int c8s = (c8 ^ l8) * 8;  // pre-swizzled global source slot (elems)
#define STAGE_TILE(bi, ktile)                                                   \
  {                                                                             \
    _Pragma("unroll") for (int i = 0; i < 2; i++) {                             \
      const int rb = (i * 4 + w) * 8 + l8;                                      \
      gl_lds16(kbase + (size_t)((ktile) * 64 + rb) * 3072 + c8s,                \
               &sK[bi][(i * 4 + w) * 512]);                                     \
      gl_lds16(vbase + (size_t)rb * 2048 + (ktile) * 64 + c8s,                  \
               &sV[bi][(i * 4 + w) * 512]);                                     \
    }                                                                           \
  }

  f32x4 oacc[2][4];
#pragma unroll
  for (int m = 0; m < 2; m++)
#pragma unroll
    for (int i = 0; i < 4; i++) oacc[m][i] = (f32x4){0.f, 0.f, 0.f, 0.f};
  float mrow[2][4], lrow[2][4];
#pragma unroll
  for (int m = 0; m < 2; m++)
#pragma unroll
    for (int rr = 0; rr < 4; rr++) { mrow[m][rr] = NEG; lrow[m][rr] = 0.f; }

  const int nkt = (qt + 1) * 2;
  STAGE_TILE(0, 0);
  asm volatile("s_waitcnt vmcnt(0)" ::: "memory");
  __syncthreads();
  int cur = 0;

  for (int kt = 0; kt < nkt; ++kt) {
    if (kt + 1 < nkt) STAGE_TILE(cur ^ 1, kt + 1);

    if (kt * 64 <= qr0 + 31) {  // wave has visible keys in this tile
      // ---- S = (Q K^T) * scale, exp2 domain ----
      f32x4 s[2][4];
      __builtin_amdgcn_s_setprio(1);
#pragma unroll
      for (int nf = 0; nf < 4; nf++) {
        const bf16x8 bk0 = *(const bf16x8*)&sK[cur][(nf * 16 + cr) * 64 + sg0];
        const bf16x8 bk1 = *(const bf16x8*)&sK[cur][(nf * 16 + cr) * 64 + sg1];
#pragma unroll
        for (int m = 0; m < 2; m++) {
          f32x4 z = (f32x4){0.f, 0.f, 0.f, 0.f};
          z = __builtin_amdgcn_mfma_f32_16x16x32_bf16(aq[m][0], bk0, z, 0, 0, 0);
          z = __builtin_amdgcn_mfma_f32_16x16x32_bf16(aq[m][1], bk1, z, 0, 0, 0);
          s[m][nf] = z * SC2;
        }
      }
      __builtin_amdgcn_s_setprio(0);
      // ---- causal mask (diagonal region only) ----
      if (kt * 64 + 63 > qr0) {
#pragma unroll
        for (int m = 0; m < 2; m++)
#pragma unroll
          for (int nf = 0; nf < 4; nf++)
#pragma unroll
            for (int rr = 0; rr < 4; rr++) {
              const int kvcol = kt * 64 + nf * 16 + cr;
              const int qrow = qr0 + m * 16 + g * 4 + rr;
              if (kvcol > qrow) s[m][nf][rr] = NEG;
            }
      }
      // ---- per m-frag: online softmax + P bounce + PV ----
#pragma unroll
      for (int m = 0; m < 2; m++) {
        float scl[4];
#pragma unroll
        for (int rr = 0; rr < 4; rr++) {
          float v = fmaxf(fmaxf(s[m][0][rr], s[m][1][rr]),
                          fmaxf(s[m][2][rr], s[m][3][rr]));
          v = fmaxf(v, __shfl_xor(v, 1));
          v = fmaxf(v, __shfl_xor(v, 2));
          v = fmaxf(v, __shfl_xor(v, 4));
          v = fmaxf(v, __shfl_xor(v, 8));
          const float mn = fmaxf(mrow[m][rr], v);
          scl[rr] = exp2f(mrow[m][rr] - mn);
          mrow[m][rr] = mn;
        }
        float rsum[4] = {0.f, 0.f, 0.f, 0.f};
#pragma unroll
        for (int nf = 0; nf < 4; nf++)
#pragma unroll
          for (int rr = 0; rr < 4; rr++) {
            const float p = exp2f(s[m][nf][rr] - mrow[m][rr]);
            s[m][nf][rr] = p;
            rsum[rr] += p;
          }
#pragma unroll
        for (int rr = 0; rr < 4; rr++) {
          float v = rsum[rr];
          v += __shfl_xor(v, 1);
          v += __shfl_xor(v, 2);
          v += __shfl_xor(v, 4);
          v += __shfl_xor(v, 8);
          lrow[m][rr] = lrow[m][rr] * scl[rr] + v;
        }
#pragma unroll
        for (int nf = 0; nf < 4; nf++) {
          f32x4 t = oacc[m][nf];
          t[0] *= scl[0]; t[1] *= scl[1]; t[2] *= scl[2]; t[3] *= scl[3];
          oacc[m][nf] = t;
        }
        // P write: swizzled byte slot within the row (involution w/ read)
#pragma unroll
        for (int nf = 0; nf < 4; nf++)
#pragma unroll
          for (int rr = 0; rr < 4; rr++) {
            const int prow = g * 4 + rr;
            pl[w][prow][(nf * 16 + cr) ^ ((prow & 7) << 3)] =
                __float2bfloat16(s[m][nf][rr]);
          }
        const bf16x8 pa0 = *(const bf16x8*)&pl[w][cr][sg0];
        const bf16x8 pa1 = *(const bf16x8*)&pl[w][cr][sg1];
        __builtin_amdgcn_s_setprio(1);
#pragma unroll
        for (int nf = 0; nf < 4; nf++) {
          const bf16x8 bv0 = *(const bf16x8*)&sV[cur][(nf * 16 + cr) * 64 + sg0];
          const bf16x8 bv1 = *(const bf16x8*)&sV[cur][(nf * 16 + cr) * 64 + sg1];
          oacc[m][nf] = __builtin_amdgcn_mfma_f32_16x16x32_bf16(pa0, bv0, oacc[m][nf], 0, 0, 0);
          oacc[m][nf] = __builtin_amdgcn_mfma_f32_16x16x32_bf16(pa1, bv1, oacc[m][nf], 0, 0, 0);
        }
        __builtin_amdgcn_s_setprio(0);
      }
    }

    if (kt + 1 < nkt) {
      asm volatile("s_waitcnt vmcnt(0)" ::: "memory");
      __syncthreads();
      cur ^= 1;
    }
  }

  // ---- write O ----
#pragma unroll
  for (int m = 0; m < 2; m++)
#pragma unroll
    for (int nf = 0; nf < 4; nf++)
#pragma unroll
      for (int rr = 0; rr < 4; rr++) {
        const int row = qr0 + m * 16 + g * 4 + rr;
        o[(size_t)(b * 2048 + row) * 1024 + h * 64 + nf * 16 + cr] =
            __float2bfloat16(oacc[m][nf][rr] / lrow[m][rr]);
      }
#undef STAGE_TILE
}

// ---------------------------------------------------------------------------
// Launch
// ---------------------------------------------------------------------------
extern "C" void kernel_launch(void* const* d_in, const int* in_sizes, int n_in,
                              void* d_out, int out_size, void* d_ws, size_t ws_size,
                              hipStream_t stream) {
  const float* x   = (const float*)d_in[0];
  const float* Wq  = (const float*)d_in[1];
  const float* Wk  = (const float*)d_in[2];
  const float* Wv  = (const float*)d_in[3];
  const float* Wo  = (const float*)d_in[4];
  const float* bo  = (const float*)d_in[5];
  const float* W1  = (const float*)d_in[6];
  const float* b1  = (const float*)d_in[7];
  const float* W2  = (const float*)d_in[8];
  const float* b2  = (const float*)d_in[9];
  const float* g1  = (const float*)d_in[10];
  const float* be1 = (const float*)d_in[11];
  const float* g2  = (const float*)d_in[12];
  const float* be2 = (const float*)d_in[13];

  char* ws = (char*)d_ws;
  const size_t MB = 1024 * 1024;
  __hip_bfloat16* hA    = (__hip_bfloat16*)(ws + 0);          // 16MB (LN1 out)
  __hip_bfloat16* attnO = (__hip_bfloat16*)(ws + 0);          // 16MB (reuse)
  __hip_bfloat16* qkv   = (__hip_bfloat16*)(ws + 16 * MB);    // 48MB
  float*          x2    = (float*)(ws + 16 * MB);             // 32MB (reuse qkv)
  __hip_bfloat16* h2    = (__hip_bfloat16*)(ws + 48 * MB);    // 16MB (reuse qkv tail)
  __hip_bfloat16* vtg   = (__hip_bfloat16*)(ws + 64 * MB);    // 16MB (dead after attn)
  __hip_bfloat16* act   = (__hip_bfloat16*)(ws + 64 * MB);    // 64MB (FFN1 out, after attn)
  __hip_bfloat16* WqkvT = (__hip_bfloat16*)(ws + 128 * MB);   // 6MB  [3072,1024]
  __hip_bfloat16* WoT   = (__hip_bfloat16*)(ws + 134 * MB);   // 2MB  [1024,1024]
  __hip_bfloat16* W1T   = (__hip_bfloat16*)(ws + 136 * MB);   // 8MB  [4096,1024]
  __hip_bfloat16* W2T   = (__hip_bfloat16*)(ws + 144 * MB);   // 8MB  [1024,4096]

  const dim3 tb(32, 8);
  tcvt_kernel<<<dim3(32, 32), tb, 0, stream>>>(Wq, WqkvT, 1024, 1024);
  tcvt_kernel<<<dim3(32, 32), tb, 0, stream>>>(Wk, WqkvT + 1024 * 1024, 1024, 1024);
  tcvt_kernel<<<dim3(32, 32), tb, 0, stream>>>(Wv, WqkvT + 2 * 1024 * 1024, 1024, 1024);
  tcvt_kernel<<<dim3(32, 32), tb, 0, stream>>>(Wo, WoT, 1024, 1024);
  tcvt_kernel<<<dim3(128, 32), tb, 0, stream>>>(W1, W1T, 1024, 4096);
  tcvt_kernel<<<dim3(32, 128), tb, 0, stream>>>(W2, W2T, 4096, 1024);

  ln_kernel<<<8192, 256, 0, stream>>>(x, g1, be1, hA);
  gemm_bt<0><<<dim3(64, 24), 256, 0, stream>>>(hA, WqkvT, qkv, nullptr, nullptr,
                                               8192, 3072, 1024);
  vtr_kernel<<<dim3(64, 2, 64), tb, 0, stream>>>(qkv, vtg);
  attn_kernel<<<1024, 256, 0, stream>>>(qkv, vtg, attnO);
  gemm_bt<1><<<dim3(64, 8), 256, 0, stream>>>(attnO, WoT, x2, bo, x, 8192, 1024, 1024);
  ln_kernel<<<8192, 256, 0, stream>>>(x2, g2, be2, h2);
  gemm_bt<2><<<dim3(64, 32), 256, 0, stream>>>(h2, W1T, act, b1, nullptr,
                                               8192, 4096, 1024);
  gemm_bt<1><<<dim3(64, 8), 256, 0, stream>>>(act, W2T, (float*)d_out, b2, x2,
                                              8192, 1024, 4096);
  (void)in_sizes; (void)n_in; (void)out_size; (void)ws_size;
}